// Round 1
// 1170.844 us; speedup vs baseline: 1.0982x; 1.0982x over previous
//
#include <hip/hip_runtime.h>
#include <hip/hip_bf16.h>

// Problem dims (fixed by reference)
#define ND 50000
#define NP 20000
#define ED 65536
#define EP 65536
#define BB 4096
#define EPS 1e-5f

// padded dims
#define KP_P 2816       // 2812 -> 88*32
#define KF_P 3392       // 3372 -> 106*32
#define LDF  3392

typedef __bf16 bf16_t;
typedef __bf16 bf16x8 __attribute__((ext_vector_type(8)));
typedef float f32x4 __attribute__((ext_vector_type(4)));

// ======================= bf16 MFMA GEMM (m97 structure) =======================
// C = A[M,K] @ Bt[N,K]^T. M%128==0, N%128==0, K%32==0.
// Epilogue: optional bias[col], optional leaky; writes to Cf (f32, ldcf) and/or Cb (bf16, ldcb).

__device__ __forceinline__ void load_lds16(const bf16_t* g, bf16_t* l) {
    __builtin_amdgcn_global_load_lds(
        (const __attribute__((address_space(1))) unsigned int*)g,
        (__attribute__((address_space(3))) unsigned int*)l,
        16, 0, 0);
}

__global__ __launch_bounds__(256) void gemm_bf16(
    const bf16_t* __restrict__ A, const bf16_t* __restrict__ Bt,
    float* __restrict__ Cf, int ldcf,
    bf16_t* __restrict__ Cb, int ldcb,
    const float* __restrict__ bias,
    int M, int N, int K, int leaky)
{
    __shared__ __align__(16) bf16_t As[128][32];
    __shared__ __align__(16) bf16_t Bs[128][32];
    const int tid = threadIdx.x;
    const int wave = tid >> 6, lane = tid & 63;
    const int quad = lane >> 4, r16 = lane & 15;
    const int wm = (wave >> 1) * 64, wn = (wave & 1) * 64;
    const int row0 = blockIdx.y * 128, col0 = blockIdx.x * 128;

    f32x4 acc[4][4] = {};

    const bf16_t* aBase = A + (size_t)(row0 + (tid >> 2)) * K + (tid & 3) * 8;
    const bf16_t* bBase = Bt + (size_t)(col0 + (tid >> 2)) * K + (tid & 3) * 8;
    bf16_t* lA = &As[0][0] + tid * 8;
    bf16_t* lB = &Bs[0][0] + tid * 8;
    const size_t rowStep = (size_t)64 * K;

    for (int k0 = 0; k0 < K; k0 += 32) {
        load_lds16(aBase + k0, lA);
        load_lds16(aBase + k0 + rowStep, lA + 2048);
        load_lds16(bBase + k0, lB);
        load_lds16(bBase + k0 + rowStep, lB + 2048);
        __syncthreads();
        bf16x8 af[4], bfr[4];
        #pragma unroll
        for (int i = 0; i < 4; i++)
            af[i] = *(const bf16x8*)&As[wm + i * 16 + r16][quad * 8];
        #pragma unroll
        for (int j = 0; j < 4; j++)
            bfr[j] = *(const bf16x8*)&Bs[wn + j * 16 + r16][quad * 8];
        #pragma unroll
        for (int i = 0; i < 4; i++)
            #pragma unroll
            for (int j = 0; j < 4; j++)
                acc[i][j] = __builtin_amdgcn_mfma_f32_16x16x32_bf16(af[i], bfr[j], acc[i][j], 0, 0, 0);
        __syncthreads();
    }

    #pragma unroll
    for (int i = 0; i < 4; i++) {
        int rowb = row0 + wm + i * 16 + quad * 4;
        #pragma unroll
        for (int j = 0; j < 4; j++) {
            int col = col0 + wn + j * 16 + r16;
            float bv = bias ? bias[col] : 0.f;
            #pragma unroll
            for (int rg = 0; rg < 4; rg++) {
                float v = acc[i][j][rg] + bv;
                if (leaky) v = (v >= 0.f) ? v : 0.01f * v;
                int row = rowb + rg;
                if (Cf) Cf[(size_t)row * ldcf + col] = v;
                if (Cb) Cb[(size_t)row * ldcb + col] = (bf16_t)v;
            }
        }
    }
}

// ======================= conversion / transpose =======================
// W [K,N] fp32 -> Wt [N,Kp] bf16 (zero-pad K..Kp)
__global__ void transpose_convert(const float* __restrict__ W, bf16_t* __restrict__ Wt,
                                  int K, int N, int Kp) {
    __shared__ float t[32][33];
    int kb = blockIdx.y * 32, nb = blockIdx.x * 32;
    int tx = threadIdx.x & 31, ty = threadIdx.x >> 5;   // 32x8
    #pragma unroll
    for (int dy = 0; dy < 32; dy += 8) {
        int k = kb + ty + dy, n = nb + tx;
        t[ty + dy][tx] = (k < K && n < N) ? W[(size_t)k * N + n] : 0.f;
    }
    __syncthreads();
    #pragma unroll
    for (int dy = 0; dy < 32; dy += 8) {
        int n = nb + ty + dy, k = kb + tx;
        if (n < N && k < Kp) Wt[(size_t)n * Kp + k] = (bf16_t)t[tx][ty + dy];
    }
}

// ======================= GCN (CSR-by-dst gather aggregation) =======================
__global__ void deg_kernel(const int* __restrict__ dst, const float* __restrict__ w,
                           float* __restrict__ deg, int E) {
    int e = blockIdx.x * blockDim.x + threadIdx.x;
    if (e < E) atomicAdd(&deg[dst[e]], w[e]);
}

__global__ void dis_kernel(const float* __restrict__ deg, float* __restrict__ dis, int N) {
    int n = blockIdx.x * blockDim.x + threadIdx.x;
    if (n < N) dis[n] = rsqrtf(deg[n] + 1.0f);
}

__global__ void claim_kernel(const int* __restrict__ idx, int* __restrict__ map, int Bn) {
    int i = blockIdx.x * blockDim.x + threadIdx.x;
    if (i < Bn) atomicCAS(&map[idx[i]], -1, i);
}

// count incoming selected edges per slot
__global__ void count_edges(const int* __restrict__ dst, const int* __restrict__ map,
                            int* __restrict__ cnt, int E) {
    int e = blockIdx.x * blockDim.x + threadIdx.x;
    if (e >= E) return;
    int slot = map[dst[e]];
    if (slot >= 0) atomicAdd(&cnt[slot], 1);
}

// self-loop counts as one extra edge for winner slots
__global__ void count_self(const int* __restrict__ idx, const int* __restrict__ map,
                           int* __restrict__ cnt, int Bn) {
    int i = blockIdx.x * blockDim.x + threadIdx.x;
    if (i >= Bn) return;
    if (map[idx[i]] == i) atomicAdd(&cnt[i], 1);
}

// exclusive scan over BB=4096 counts, single block of 1024 threads x 4 elems
__global__ void scan4k(const int* __restrict__ cnt, int* __restrict__ start,
                       int* __restrict__ cur) {
    __shared__ int part[1024];
    int tid = threadIdx.x;
    int base = tid * 4;
    int a0 = cnt[base], a1 = cnt[base + 1], a2 = cnt[base + 2], a3 = cnt[base + 3];
    int s = a0 + a1 + a2 + a3;
    part[tid] = s;
    __syncthreads();
    #pragma unroll
    for (int off = 1; off < 1024; off <<= 1) {
        int v = (tid >= off) ? part[tid - off] : 0;
        __syncthreads();
        part[tid] += v;
        __syncthreads();
    }
    int excl = part[tid] - s;
    int p0 = excl, p1 = excl + a0, p2 = p1 + a1, p3 = p2 + a2;
    start[base] = p0; start[base + 1] = p1; start[base + 2] = p2; start[base + 3] = p3;
    cur[base] = p0;   cur[base + 1] = p1;   cur[base + 2] = p2;   cur[base + 3] = p3;
    if (tid == 1023) start[BB] = excl + s;
}

__global__ void fill_edges(const int* __restrict__ src, const int* __restrict__ dst,
                           const float* __restrict__ w, const float* __restrict__ dis,
                           const int* __restrict__ map, int* __restrict__ cur,
                           int* __restrict__ esrc, float* __restrict__ enorm, int E) {
    int e = blockIdx.x * blockDim.x + threadIdx.x;
    if (e >= E) return;
    int d = dst[e];
    int slot = map[d];
    if (slot < 0) return;
    int s = src[e];
    int p = atomicAdd(&cur[slot], 1);
    esrc[p] = s;
    enorm[p] = dis[s] * w[e] * dis[d];
}

__global__ void fill_self(const int* __restrict__ idx, const int* __restrict__ map,
                          const float* __restrict__ dis, int* __restrict__ cur,
                          int* __restrict__ esrc, float* __restrict__ enorm, int Bn) {
    int i = blockIdx.x * blockDim.x + threadIdx.x;
    if (i >= Bn) return;
    int n = idx[i];
    if (map[n] != i) return;
    int p = atomicAdd(&cur[i], 1);
    esrc[p] = n;
    enorm[p] = dis[n] * dis[n];
}

// One block per (slot, 256-col chunk). Register accumulation over the slot's
// edge list; single bf16 write (zero-padded to Fp). No atomics.
__global__ void gather_rows(const int* __restrict__ start, const int* __restrict__ esrc,
                            const float* __restrict__ enorm, const float* __restrict__ A,
                            bf16_t* __restrict__ aggb, int F, int Fp) {
    int slot = blockIdx.x;
    int f = blockIdx.y * 256 + threadIdx.x;
    int s0 = start[slot], s1 = start[slot + 1];
    __shared__ int ls[256];
    __shared__ float lw[256];
    float acc = 0.f;
    for (int b = s0; b < s1; b += 256) {
        int nb = min(s1 - b, 256);
        __syncthreads();
        if (threadIdx.x < nb) {
            ls[threadIdx.x] = esrc[b + threadIdx.x];
            lw[threadIdx.x] = enorm[b + threadIdx.x];
        }
        __syncthreads();
        if (f < F)
            for (int e = 0; e < nb; e++)
                acc += lw[e] * A[(size_t)ls[e] * F + f];
    }
    if (f < Fp) aggb[(size_t)slot * Fp + f] = (bf16_t)acc;
}

// Duplicate batch indices: copy winner's GCN output row into dup rows.
__global__ void fix_dups(const int* __restrict__ idx, const int* __restrict__ map,
                         bf16_t* __restrict__ featb, int colOff) {
    int i = blockIdx.x;
    int s = map[idx[i]];
    if (s == i) return;
    bf16_t* dstp = featb + (size_t)i * LDF + colOff;
    const bf16_t* srcp = featb + (size_t)s * LDF + colOff;
    for (int f = threadIdx.x; f < 1024; f += blockDim.x)
        dstp[f] = srcp[f];
}

__global__ void copy_cols_b(const float* __restrict__ X, bf16_t* __restrict__ featb,
                            int C, int colOff, size_t total) {
    size_t i = (size_t)blockIdx.x * blockDim.x + threadIdx.x;
    if (i >= total) return;
    int r = (int)(i / C), c = (int)(i % C);
    featb[(size_t)r * LDF + colOff + c] = (bf16_t)X[i];
}

// ======================= BatchNorm (training mode) =======================
__global__ void bn_stats(const float* __restrict__ X, float* __restrict__ stats,
                         int C, int rowsPerBlock) {
    int c = blockIdx.x * blockDim.x + threadIdx.x;
    if (c >= C) return;
    int r0 = blockIdx.y * rowsPerBlock;
    int r1 = r0 + rowsPerBlock;
    float s1 = 0.f, s2 = 0.f;
    for (int r = r0; r < r1; r++) {
        float v = X[(size_t)r * C + c];
        s1 += v;
        s2 += v * v;
    }
    atomicAdd(&stats[c], s1);
    atomicAdd(&stats[C + c], s2);
}

__global__ void bn_apply(const float* __restrict__ X, const float* __restrict__ stats,
                         const float* __restrict__ gamma, const float* __restrict__ beta,
                         float* __restrict__ Yf, bf16_t* __restrict__ Yb,
                         int C, int leaky, size_t total) {
    size_t i = (size_t)blockIdx.x * blockDim.x + threadIdx.x;
    if (i >= total) return;
    int c = (int)(i % C);
    float m = stats[c] * (1.f / BB);
    float v = stats[C + c] * (1.f / BB) - m * m;
    float xn = (X[i] - m) * rsqrtf(v + EPS) * gamma[c] + beta[c];
    if (leaky) xn = (xn >= 0.f) ? xn : 0.01f * xn;
    if (Yf) Yf[i] = xn;
    if (Yb) Yb[i] = (bf16_t)xn;
}

// ======================= final y = o @ W_o2 + b =======================
__global__ void rowdot_kernel(const float* __restrict__ X, const float* __restrict__ Wv,
                              const float* __restrict__ b, float* __restrict__ y, int K) {
    int row = blockIdx.x * (blockDim.x >> 6) + (threadIdx.x >> 6);
    int lane = threadIdx.x & 63;
    if (row >= BB) return;
    float s = 0.f;
    for (int k = lane; k < K; k += 64) s += X[(size_t)row * K + k] * Wv[k];
    #pragma unroll
    for (int off = 32; off > 0; off >>= 1) s += __shfl_down(s, off);
    if (lane == 0) y[row] = s + b[0];
}

// ======================= launch =======================
extern "C" void kernel_launch(void* const* d_in, const int* in_sizes, int n_in,
                              void* d_out, int out_size, void* d_ws, size_t ws_size,
                              hipStream_t stream) {
    const int*   d_index = (const int*)d_in[0];
    const int*   p_index = (const int*)d_in[1];
    const float* d_vecs  = (const float*)d_in[2];
    const float* p_emb   = (const float*)d_in[3];
    const float* d_ecfps = (const float*)d_in[4];
    const int*   d_eidx  = (const int*)d_in[5];
    const float* d_ew    = (const float*)d_in[6];
    const float* p_gos   = (const float*)d_in[7];
    const int*   p_eidx  = (const int*)d_in[8];
    const float* p_ew    = (const float*)d_in[9];
    const float* W_dg = (const float*)d_in[10];
    const float* b_dg = (const float*)d_in[11];
    const float* W_pg = (const float*)d_in[12];
    const float* b_pg = (const float*)d_in[13];
    const float* W_e1 = (const float*)d_in[14];
    // b_e1 cancels under BN (per-column shift invariance)
    const float* g_e1 = (const float*)d_in[16];
    const float* be_e1= (const float*)d_in[17];
    const float* W_e2 = (const float*)d_in[18];
    // b_e2 cancels under BN
    const float* g_e2 = (const float*)d_in[20];
    const float* be_e2= (const float*)d_in[21];
    const float* W_o1 = (const float*)d_in[22];
    const float* b_o1 = (const float*)d_in[23];   // pre-leaky: must apply
    const float* g_o  = (const float*)d_in[24];
    const float* be_o = (const float*)d_in[25];
    const float* W_o2 = (const float*)d_in[26];
    const float* b_o2 = (const float*)d_in[27];

    // ---- workspace layout ----
    char* w = (char*)d_ws;
    bf16_t* aggb  = (bf16_t*)w;  w += (size_t)BB * KP_P * 2;     // 23.1 MB (GEMM A input, bf16)
    bf16_t* featb = (bf16_t*)w;  w += (size_t)BB * LDF * 2;      // 27.8 MB
    bf16_t* Wt_dg = (bf16_t*)w;  w += (size_t)1024 * 1024 * 2;
    bf16_t* Wt_pg = (bf16_t*)w;  w += (size_t)1024 * KP_P * 2;
    bf16_t* Wt_e1 = (bf16_t*)w;  w += (size_t)2048 * KF_P * 2;
    bf16_t* Wt_e2 = (bf16_t*)w;  w += (size_t)1024 * 2048 * 2;
    bf16_t* Wt_o1 = (bf16_t*)w;  w += (size_t)256 * 1024 * 2;
    float*  deg   = (float*)w;   w += (size_t)ND * 4;
    float*  dis   = (float*)w;   w += (size_t)ND * 4;
    int*    map   = (int*)w;     w += (size_t)ND * 4;
    int*    cnt   = (int*)w;     w += (size_t)BB * 4;
    int*    startA= (int*)w;     w += (size_t)(BB + 4) * 4;
    int*    cur   = (int*)w;     w += (size_t)BB * 4;
    int*    esrc  = (int*)w;     w += (size_t)(EP + BB) * 4;
    float*  enorm = (float*)w;   w += (size_t)(EP + BB) * 4;
    float*  Z1    = (float*)w;   w += (size_t)BB * 2048 * 4;     // 33.6 MB
    bf16_t* Z1b   = (bf16_t*)w;  w += (size_t)BB * 2048 * 2;
    float*  Z2    = (float*)w;   w += (size_t)BB * 1024 * 4;
    bf16_t* feat2b= (bf16_t*)w;  w += (size_t)BB * 1024 * 2;
    float*  Z3    = (float*)w;   w += (size_t)BB * 256 * 4;
    float*  Z3n   = (float*)w;   w += (size_t)BB * 256 * 4;
    float*  stats = (float*)w;   w += 16384;

    float* y     = (float*)d_out;
    float* feat2 = (float*)d_out + BB;

    dim3 blk256(256);

    // ---- weight transposes ----
    transpose_convert<<<dim3(1024/32, 1024/32), blk256, 0, stream>>>(W_dg, Wt_dg, 1024, 1024, 1024);
    transpose_convert<<<dim3(1024/32, KP_P/32), blk256, 0, stream>>>(W_pg, Wt_pg, 2812, 1024, KP_P);
    transpose_convert<<<dim3(2048/32, KF_P/32), blk256, 0, stream>>>(W_e1, Wt_e1, 3372, 2048, KF_P);
    transpose_convert<<<dim3(1024/32, 2048/32), blk256, 0, stream>>>(W_e2, Wt_e2, 2048, 1024, 2048);
    transpose_convert<<<dim3(256/32, 1024/32), blk256, 0, stream>>>(W_o1, Wt_o1, 1024, 256, 1024);

    // ============ drug branch (F=1024) ============
    hipMemsetAsync(deg, 0, ND * sizeof(float), stream);
    hipMemsetAsync(map, 0xFF, ND * sizeof(int), stream);
    hipMemsetAsync(cnt, 0, BB * sizeof(int), stream);

    deg_kernel<<<dim3((ED + 255) / 256), blk256, 0, stream>>>(d_eidx + ED, d_ew, deg, ED);
    dis_kernel<<<dim3((ND + 255) / 256), blk256, 0, stream>>>(deg, dis, ND);
    claim_kernel<<<dim3((BB + 255) / 256), blk256, 0, stream>>>(d_index, map, BB);
    count_edges<<<dim3((ED + 255) / 256), blk256, 0, stream>>>(d_eidx + ED, map, cnt, ED);
    count_self<<<dim3((BB + 255) / 256), blk256, 0, stream>>>(d_index, map, cnt, BB);
    scan4k<<<dim3(1), dim3(1024), 0, stream>>>(cnt, startA, cur);
    fill_edges<<<dim3((ED + 255) / 256), blk256, 0, stream>>>(d_eidx, d_eidx + ED, d_ew, dis,
                                                              map, cur, esrc, enorm, ED);
    fill_self<<<dim3((BB + 255) / 256), blk256, 0, stream>>>(d_index, map, dis, cur, esrc, enorm, BB);
    gather_rows<<<dim3(BB, 1024/256), blk256, 0, stream>>>(startA, esrc, enorm, d_ecfps,
                                                           aggb, 1024, 1024);
    gemm_bf16<<<dim3(1024/128, BB/128), blk256, 0, stream>>>(aggb, Wt_dg, nullptr, 0,
                                                             featb + 1324, LDF, b_dg, BB, 1024, 1024, 1);
    fix_dups<<<dim3(BB), blk256, 0, stream>>>(d_index, map, featb, 1324);

    // ============ protein branch (F=2812) ============
    hipMemsetAsync(deg, 0, NP * sizeof(float), stream);
    hipMemsetAsync(map, 0xFF, NP * sizeof(int), stream);
    hipMemsetAsync(cnt, 0, BB * sizeof(int), stream);

    deg_kernel<<<dim3((EP + 255) / 256), blk256, 0, stream>>>(p_eidx + EP, p_ew, deg, EP);
    dis_kernel<<<dim3((NP + 255) / 256), blk256, 0, stream>>>(deg, dis, NP);
    claim_kernel<<<dim3((BB + 255) / 256), blk256, 0, stream>>>(p_index, map, BB);
    count_edges<<<dim3((EP + 255) / 256), blk256, 0, stream>>>(p_eidx + EP, map, cnt, EP);
    count_self<<<dim3((BB + 255) / 256), blk256, 0, stream>>>(p_index, map, cnt, BB);
    scan4k<<<dim3(1), dim3(1024), 0, stream>>>(cnt, startA, cur);
    fill_edges<<<dim3((EP + 255) / 256), blk256, 0, stream>>>(p_eidx, p_eidx + EP, p_ew, dis,
                                                              map, cur, esrc, enorm, EP);
    fill_self<<<dim3((BB + 255) / 256), blk256, 0, stream>>>(p_index, map, dis, cur, esrc, enorm, BB);
    gather_rows<<<dim3(BB, KP_P/256), blk256, 0, stream>>>(startA, esrc, enorm, p_gos,
                                                           aggb, 2812, KP_P);
    gemm_bf16<<<dim3(1024/128, BB/128), blk256, 0, stream>>>(aggb, Wt_pg, nullptr, 0,
                                                             featb + 2348, LDF, b_pg, BB, 1024, KP_P, 1);
    fix_dups<<<dim3(BB), blk256, 0, stream>>>(p_index, map, featb, 2348);

    // ============ dense concat ============
    {
        size_t t1 = (size_t)BB * 300, t2 = (size_t)BB * 1024;
        copy_cols_b<<<dim3((t1 + 255) / 256), blk256, 0, stream>>>(d_vecs, featb, 300, 0, t1);
        copy_cols_b<<<dim3((t2 + 255) / 256), blk256, 0, stream>>>(p_emb, featb, 1024, 300, t2);
    }

    // ============ e1: Z1 = featb @ W_e1; BN+leaky -> Z1b ============
    gemm_bf16<<<dim3(2048/128, BB/128), blk256, 0, stream>>>(featb, Wt_e1, Z1, 2048, nullptr, 0,
                                                             nullptr, BB, 2048, KF_P, 0);
    hipMemsetAsync(stats, 0, 2 * 2048 * sizeof(float), stream);
    bn_stats<<<dim3(2048/256, BB/256), blk256, 0, stream>>>(Z1, stats, 2048, 256);
    bn_apply<<<dim3(((size_t)BB*2048 + 255) / 256), blk256, 0, stream>>>(Z1, stats, g_e1, be_e1,
                                                                          nullptr, Z1b, 2048, 1, (size_t)BB*2048);

    // ============ e2: Z2 = Z1b @ W_e2; BN+leaky -> feat2 (f32 out) + feat2b ============
    gemm_bf16<<<dim3(1024/128, BB/128), blk256, 0, stream>>>(Z1b, Wt_e2, Z2, 1024, nullptr, 0,
                                                             nullptr, BB, 1024, 2048, 0);
    hipMemsetAsync(stats, 0, 2 * 1024 * sizeof(float), stream);
    bn_stats<<<dim3(1024/256, BB/256), blk256, 0, stream>>>(Z2, stats, 1024, 256);
    bn_apply<<<dim3(((size_t)BB*1024 + 255) / 256), blk256, 0, stream>>>(Z2, stats, g_e2, be_e2,
                                                                          feat2, feat2b, 1024, 1, (size_t)BB*1024);

    // ============ o1: Z3 = leaky(feat2b @ W_o1 + b_o1); BN -> Z3n; y ============
    gemm_bf16<<<dim3(256/128, BB/128), blk256, 0, stream>>>(feat2b, Wt_o1, Z3, 256, nullptr, 0,
                                                            b_o1, BB, 256, 1024, 1);
    hipMemsetAsync(stats, 0, 2 * 256 * sizeof(float), stream);
    bn_stats<<<dim3(1, BB/256), blk256, 0, stream>>>(Z3, stats, 256, 256);
    bn_apply<<<dim3(((size_t)BB*256 + 255) / 256), blk256, 0, stream>>>(Z3, stats, g_o, be_o,
                                                                         Z3n, nullptr, 256, 0, (size_t)BB*256);
    rowdot_kernel<<<dim3(BB/4), blk256, 0, stream>>>(Z3n, W_o2, b_o2, y, 256);
}

// Round 2
// 871.319 us; speedup vs baseline: 1.4757x; 1.3438x over previous
//
#include <hip/hip_runtime.h>
#include <hip/hip_bf16.h>

// Problem dims (fixed by reference)
#define ND 50000
#define NP 20000
#define ED 65536
#define EP 65536
#define BB 4096
#define EPS 1e-5f

// padded dims
#define KP_P 2816       // 2812 -> 88*32
#define KF_P 3392       // 3372 -> 106*32
#define LDF  3392

typedef __bf16 bf16_t;
typedef __bf16 bf16x8 __attribute__((ext_vector_type(8)));
typedef float f32x4 __attribute__((ext_vector_type(4)));

// ======================= bf16 MFMA GEMM (m97 structure) =======================
// C = A[M,K] @ Bt[N,K]^T. Grid (N/128, M/128[, z]). Epilogue: optional bias,
// optional leaky, writes f32 and/or bf16, optional per-column BN stats
// (sum, sumsq from exact f32 accumulators) via atomics.

struct GemmP {
    const bf16_t* A;
    const bf16_t* Bt;
    float* Cf; int ldcf;
    bf16_t* Cb; int ldcb;
    const float* bias;
    int K;
    int leaky;
};

__device__ __forceinline__ void load_lds16(const bf16_t* g, bf16_t* l) {
    __builtin_amdgcn_global_load_lds(
        (const __attribute__((address_space(1))) unsigned int*)g,
        (__attribute__((address_space(3))) unsigned int*)l,
        16, 0, 0);
}

__device__ __forceinline__ void gemm_body(const GemmP p, float* stats, int statsC,
                                          bf16_t (*As)[32], bf16_t (*Bs)[32]) {
    const int tid = threadIdx.x;
    const int wave = tid >> 6, lane = tid & 63;
    const int quad = lane >> 4, r16 = lane & 15;
    const int wm = (wave >> 1) * 64, wn = (wave & 1) * 64;
    const int row0 = blockIdx.y * 128, col0 = blockIdx.x * 128;
    const int K = p.K;

    f32x4 acc[4][4] = {};

    const bf16_t* aBase = p.A + (size_t)(row0 + (tid >> 2)) * K + (tid & 3) * 8;
    const bf16_t* bBase = p.Bt + (size_t)(col0 + (tid >> 2)) * K + (tid & 3) * 8;
    bf16_t* lA = &As[0][0] + tid * 8;
    bf16_t* lB = &Bs[0][0] + tid * 8;
    const size_t rowStep = (size_t)64 * K;

    for (int k0 = 0; k0 < K; k0 += 32) {
        load_lds16(aBase + k0, lA);
        load_lds16(aBase + k0 + rowStep, lA + 2048);
        load_lds16(bBase + k0, lB);
        load_lds16(bBase + k0 + rowStep, lB + 2048);
        __syncthreads();
        bf16x8 af[4], bfr[4];
        #pragma unroll
        for (int i = 0; i < 4; i++)
            af[i] = *(const bf16x8*)&As[wm + i * 16 + r16][quad * 8];
        #pragma unroll
        for (int j = 0; j < 4; j++)
            bfr[j] = *(const bf16x8*)&Bs[wn + j * 16 + r16][quad * 8];
        #pragma unroll
        for (int i = 0; i < 4; i++)
            #pragma unroll
            for (int j = 0; j < 4; j++)
                acc[i][j] = __builtin_amdgcn_mfma_f32_16x16x32_bf16(af[i], bfr[j], acc[i][j], 0, 0, 0);
        __syncthreads();
    }

    float s1[4] = {0.f, 0.f, 0.f, 0.f};
    float s2[4] = {0.f, 0.f, 0.f, 0.f};

    #pragma unroll
    for (int i = 0; i < 4; i++) {
        int rowb = row0 + wm + i * 16 + quad * 4;
        #pragma unroll
        for (int j = 0; j < 4; j++) {
            int col = col0 + wn + j * 16 + r16;
            float bv = p.bias ? p.bias[col] : 0.f;
            #pragma unroll
            for (int rg = 0; rg < 4; rg++) {
                float v = acc[i][j][rg] + bv;
                if (p.leaky) v = (v >= 0.f) ? v : 0.01f * v;
                int row = rowb + rg;
                if (p.Cf) p.Cf[(size_t)row * p.ldcf + col] = v;
                if (p.Cb) p.Cb[(size_t)row * p.ldcb + col] = (bf16_t)v;
                s1[j] += v;
                s2[j] += v * v;
            }
        }
    }

    if (stats) {
        // per-wave, per-j: lanes {r16, r16+16, r16+32, r16+48} hold partials
        // for the same column -> reduce over quads, lanes 0..15 commit.
        #pragma unroll
        for (int j = 0; j < 4; j++) {
            float a = s1[j], b = s2[j];
            a += __shfl_down(a, 32); b += __shfl_down(b, 32);
            a += __shfl_down(a, 16); b += __shfl_down(b, 16);
            if (lane < 16) {
                int col = col0 + wn + j * 16 + lane;
                atomicAdd(&stats[col], a);
                atomicAdd(&stats[statsC + col], b);
            }
        }
    }
}

__global__ __launch_bounds__(256) void gemm_one(GemmP p, float* stats, int statsC) {
    __shared__ __align__(16) bf16_t As[128][32];
    __shared__ __align__(16) bf16_t Bs[128][32];
    gemm_body(p, stats, statsC, As, Bs);
}

// two independent GEMMs in one launch (z selects) -> 2 blocks/CU overlap
__global__ __launch_bounds__(256) void gemm_two(GemmP p0, GemmP p1) {
    __shared__ __align__(16) bf16_t As[128][32];
    __shared__ __align__(16) bf16_t Bs[128][32];
    gemm_body(blockIdx.z ? p1 : p0, nullptr, 0, As, Bs);
}

// ======================= grouped weight transpose =======================
// W [K,N] fp32 -> Wt [N,Kp] bf16 (zero-pad K..Kp), 5 matrices, one launch.
__global__ void transpose_all(const float* __restrict__ W0, bf16_t* __restrict__ T0,
                              const float* __restrict__ W1, bf16_t* __restrict__ T1,
                              const float* __restrict__ W2, bf16_t* __restrict__ T2,
                              const float* __restrict__ W3, bf16_t* __restrict__ T3,
                              const float* __restrict__ W4, bf16_t* __restrict__ T4) {
    __shared__ float t[32][33];
    int b = blockIdx.x;
    const float* W; bf16_t* Wt; int K, N, Kp, nbx, r;
    if (b < 1024)       { W = W0; Wt = T0; K = 1024; N = 1024; Kp = 1024; nbx = 32; r = b; }
    else if (b < 3840)  { W = W1; Wt = T1; K = 2812; N = 1024; Kp = 2816; nbx = 32; r = b - 1024; }
    else if (b < 10624) { W = W2; Wt = T2; K = 3372; N = 2048; Kp = 3392; nbx = 64; r = b - 3840; }
    else if (b < 12672) { W = W3; Wt = T3; K = 2048; N = 1024; Kp = 2048; nbx = 32; r = b - 10624; }
    else                { W = W4; Wt = T4; K = 1024; N = 256;  Kp = 1024; nbx = 8;  r = b - 12672; }
    int nb = (r % nbx) * 32, kb = (r / nbx) * 32;
    int tx = threadIdx.x & 31, ty = threadIdx.x >> 5;   // 32x8
    #pragma unroll
    for (int dy = 0; dy < 32; dy += 8) {
        int k = kb + ty + dy, n = nb + tx;
        t[ty + dy][tx] = (k < K && n < N) ? W[(size_t)k * N + n] : 0.f;
    }
    __syncthreads();
    #pragma unroll
    for (int dy = 0; dy < 32; dy += 8) {
        int n = nb + ty + dy, k = kb + tx;
        if (n < N && k < Kp) Wt[(size_t)n * Kp + k] = (bf16_t)t[tx][ty + dy];
    }
}

// ======================= GCN preprocessing (both branches fused) =======================
// prep1: degree accumulation + slot claim
__global__ void prep1(const int* __restrict__ dD, const float* __restrict__ wD,
                      const int* __restrict__ dP, const float* __restrict__ wP,
                      const int* __restrict__ idxD, const int* __restrict__ idxP,
                      float* __restrict__ degD, float* __restrict__ degP,
                      int* __restrict__ mapD, int* __restrict__ mapP) {
    int t = blockIdx.x * blockDim.x + threadIdx.x;
    if (t < ED) { atomicAdd(&degD[dD[t]], wD[t]); return; }
    t -= ED;
    if (t < EP) { atomicAdd(&degP[dP[t]], wP[t]); return; }
    t -= EP;
    if (t < BB) { atomicCAS(&mapD[idxD[t]], -1, t); return; }
    t -= BB;
    if (t < BB) { atomicCAS(&mapP[idxP[t]], -1, t); }
}

// prep2: dis = rsqrt(deg+1); per-slot edge counts (incl. self-loop)
__global__ void prep2(const float* __restrict__ degD, const float* __restrict__ degP,
                      float* __restrict__ disD, float* __restrict__ disP,
                      const int* __restrict__ dD, const int* __restrict__ dP,
                      const int* __restrict__ mapD, const int* __restrict__ mapP,
                      const int* __restrict__ idxD, const int* __restrict__ idxP,
                      int* __restrict__ cntD, int* __restrict__ cntP) {
    int t = blockIdx.x * blockDim.x + threadIdx.x;
    if (t < ND) { disD[t] = rsqrtf(degD[t] + 1.0f); return; }
    t -= ND;
    if (t < NP) { disP[t] = rsqrtf(degP[t] + 1.0f); return; }
    t -= NP;
    if (t < ED) { int s = mapD[dD[t]]; if (s >= 0) atomicAdd(&cntD[s], 1); return; }
    t -= ED;
    if (t < EP) { int s = mapP[dP[t]]; if (s >= 0) atomicAdd(&cntP[s], 1); return; }
    t -= EP;
    if (t < BB) { if (mapD[idxD[t]] == t) atomicAdd(&cntD[t], 1); return; }
    t -= BB;
    if (t < BB) { if (mapP[idxP[t]] == t) atomicAdd(&cntP[t], 1); }
}

// exclusive scan over BB=4096 counts; block 0 = drug, block 1 = protein
__global__ void scan2(const int* __restrict__ cnt, int* __restrict__ start,
                      int* __restrict__ cur) {
    __shared__ int part[1024];
    const int br = blockIdx.x;
    const int* c = cnt + br * BB;
    int* st = start + br * (BB + 8);
    int* cu = cur + br * BB;
    int tid = threadIdx.x;
    int base = tid * 4;
    int a0 = c[base], a1 = c[base + 1], a2 = c[base + 2], a3 = c[base + 3];
    int s = a0 + a1 + a2 + a3;
    part[tid] = s;
    __syncthreads();
    #pragma unroll
    for (int off = 1; off < 1024; off <<= 1) {
        int v = (tid >= off) ? part[tid - off] : 0;
        __syncthreads();
        part[tid] += v;
        __syncthreads();
    }
    int excl = part[tid] - s;
    int p0 = excl, p1 = excl + a0, p2 = p1 + a1, p3 = p2 + a2;
    st[base] = p0; st[base + 1] = p1; st[base + 2] = p2; st[base + 3] = p3;
    cu[base] = p0; cu[base + 1] = p1; cu[base + 2] = p2; cu[base + 3] = p3;
    if (tid == 1023) st[BB] = excl + s;
}

// prep3: fill CSR edge lists (edges + self-loops), both branches
__global__ void prep3(const int* __restrict__ sD, const int* __restrict__ dD,
                      const float* __restrict__ wD,
                      const int* __restrict__ sP, const int* __restrict__ dP,
                      const float* __restrict__ wP,
                      const float* __restrict__ disD, const float* __restrict__ disP,
                      const int* __restrict__ mapD, const int* __restrict__ mapP,
                      const int* __restrict__ idxD, const int* __restrict__ idxP,
                      int* __restrict__ curD, int* __restrict__ curP,
                      int* __restrict__ esrcD, float* __restrict__ enormD,
                      int* __restrict__ esrcP, float* __restrict__ enormP) {
    int t = blockIdx.x * blockDim.x + threadIdx.x;
    if (t < ED) {
        int d = dD[t]; int slot = mapD[d];
        if (slot < 0) return;
        int s = sD[t];
        int p = atomicAdd(&curD[slot], 1);
        esrcD[p] = s; enormD[p] = disD[s] * wD[t] * disD[d];
        return;
    }
    t -= ED;
    if (t < EP) {
        int d = dP[t]; int slot = mapP[d];
        if (slot < 0) return;
        int s = sP[t];
        int p = atomicAdd(&curP[slot], 1);
        esrcP[p] = s; enormP[p] = disP[s] * wP[t] * disP[d];
        return;
    }
    t -= EP;
    if (t < BB) {
        int n = idxD[t];
        if (mapD[n] != t) return;
        int p = atomicAdd(&curD[t], 1);
        esrcD[p] = n; enormD[p] = disD[n] * disD[n];
        return;
    }
    t -= BB;
    if (t < BB) {
        int n = idxP[t];
        if (mapP[n] != t) return;
        int p = atomicAdd(&curP[t], 1);
        esrcP[p] = n; enormP[p] = disP[n] * disP[n];
    }
}

// Grouped gather: grid (BB, 15). y<4: drug chunk y; y>=4: protein chunk y-4.
// Register accumulation over the slot's edge list; single bf16 write. No atomics.
__global__ void gather2(const int* __restrict__ startD, const int* __restrict__ esrcD,
                        const float* __restrict__ enormD, const float* __restrict__ AD,
                        const int* __restrict__ startP, const int* __restrict__ esrcP,
                        const float* __restrict__ enormP, const float* __restrict__ AP,
                        bf16_t* __restrict__ aggbD, bf16_t* __restrict__ aggbP) {
    __shared__ int ls[256];
    __shared__ float lw[256];
    int slot = blockIdx.x;
    bool isP = blockIdx.y >= 4;
    int chunk = isP ? blockIdx.y - 4 : blockIdx.y;
    int F  = isP ? 2812 : 1024;
    int Fp = isP ? KP_P : 1024;
    const int* start = isP ? startP : startD;
    const int* esrc  = isP ? esrcP  : esrcD;
    const float* enorm = isP ? enormP : enormD;
    const float* A   = isP ? AP : AD;
    bf16_t* out = isP ? aggbP : aggbD;
    int f = chunk * 256 + threadIdx.x;
    int s0 = start[slot], s1 = start[slot + 1];
    float acc = 0.f;
    for (int b = s0; b < s1; b += 256) {
        int nb = min(s1 - b, 256);
        __syncthreads();
        if (threadIdx.x < nb) {
            ls[threadIdx.x] = esrc[b + threadIdx.x];
            lw[threadIdx.x] = enorm[b + threadIdx.x];
        }
        __syncthreads();
        if (f < F)
            for (int e = 0; e < nb; e++)
                acc += lw[e] * A[(size_t)ls[e] * F + f];
    }
    if (f < Fp) out[(size_t)slot * Fp + f] = (bf16_t)acc;
}

// Duplicate batch indices: copy winner's GCN output row into dup rows. Both branches.
__global__ void fix_dups2(const int* __restrict__ idxD, const int* __restrict__ mapD,
                          const int* __restrict__ idxP, const int* __restrict__ mapP,
                          bf16_t* __restrict__ featb) {
    int i = blockIdx.x;
    const int* idx = blockIdx.y ? idxP : idxD;
    const int* map = blockIdx.y ? mapP : mapD;
    int colOff = blockIdx.y ? 2348 : 1324;
    int s = map[idx[i]];
    if (s == i) return;
    bf16_t* dstp = featb + (size_t)i * LDF + colOff;
    const bf16_t* srcp = featb + (size_t)s * LDF + colOff;
    for (int f = threadIdx.x; f < 1024; f += blockDim.x)
        dstp[f] = srcp[f];
}

// dense concat (d_vecs cols 0..300, p_emb cols 300..1324), one launch
__global__ void copy_cols2(const float* __restrict__ X1, const float* __restrict__ X2,
                           bf16_t* __restrict__ featb) {
    size_t i = (size_t)blockIdx.x * blockDim.x + threadIdx.x;
    const size_t t1 = (size_t)BB * 300;
    const size_t t2 = (size_t)BB * 1024;
    if (i < t1) {
        int r = (int)(i / 300), c = (int)(i % 300);
        featb[(size_t)r * LDF + c] = (bf16_t)X1[i];
    } else {
        i -= t1;
        if (i >= t2) return;
        int r = (int)(i / 1024), c = (int)(i % 1024);
        featb[(size_t)r * LDF + 300 + c] = (bf16_t)X2[i];
    }
}

// ======================= BatchNorm apply (stats from GEMM epilogue) =======================
__global__ void bn_apply(const float* __restrict__ X, const float* __restrict__ stats,
                         const float* __restrict__ gamma, const float* __restrict__ beta,
                         float* __restrict__ Yf, bf16_t* __restrict__ Yb,
                         int C, int leaky, size_t total) {
    size_t i = (size_t)blockIdx.x * blockDim.x + threadIdx.x;
    if (i >= total) return;
    int c = (int)(i % C);
    float m = stats[c] * (1.f / BB);
    float v = stats[C + c] * (1.f / BB) - m * m;
    float xn = (X[i] - m) * rsqrtf(v + EPS) * gamma[c] + beta[c];
    if (leaky) xn = (xn >= 0.f) ? xn : 0.01f * xn;
    if (Yf) Yf[i] = xn;
    if (Yb) Yb[i] = (bf16_t)xn;
}

// ======================= final: y = BN(Z3) @ W_o2 + b (BN fused) =======================
__global__ void rowdot_bn(const float* __restrict__ Z3, const float* __restrict__ stats,
                          const float* __restrict__ gamma, const float* __restrict__ beta,
                          const float* __restrict__ Wv, const float* __restrict__ b,
                          float* __restrict__ y) {
    int row = blockIdx.x * (blockDim.x >> 6) + (threadIdx.x >> 6);
    int lane = threadIdx.x & 63;
    if (row >= BB) return;
    float s = 0.f;
    #pragma unroll
    for (int kk = 0; kk < 4; kk++) {
        int k = lane + kk * 64;
        float m = stats[k] * (1.f / BB);
        float v = stats[256 + k] * (1.f / BB) - m * m;
        float xn = (Z3[(size_t)row * 256 + k] - m) * rsqrtf(v + EPS) * gamma[k] + beta[k];
        s += xn * Wv[k];
    }
    #pragma unroll
    for (int off = 32; off > 0; off >>= 1) s += __shfl_down(s, off);
    if (lane == 0) y[row] = s + b[0];
}

// ======================= launch =======================
extern "C" void kernel_launch(void* const* d_in, const int* in_sizes, int n_in,
                              void* d_out, int out_size, void* d_ws, size_t ws_size,
                              hipStream_t stream) {
    const int*   d_index = (const int*)d_in[0];
    const int*   p_index = (const int*)d_in[1];
    const float* d_vecs  = (const float*)d_in[2];
    const float* p_emb   = (const float*)d_in[3];
    const float* d_ecfps = (const float*)d_in[4];
    const int*   d_eidx  = (const int*)d_in[5];
    const float* d_ew    = (const float*)d_in[6];
    const float* p_gos   = (const float*)d_in[7];
    const int*   p_eidx  = (const int*)d_in[8];
    const float* p_ew    = (const float*)d_in[9];
    const float* W_dg = (const float*)d_in[10];
    const float* b_dg = (const float*)d_in[11];
    const float* W_pg = (const float*)d_in[12];
    const float* b_pg = (const float*)d_in[13];
    const float* W_e1 = (const float*)d_in[14];
    // b_e1 cancels under BN (per-column shift invariance)
    const float* g_e1 = (const float*)d_in[16];
    const float* be_e1= (const float*)d_in[17];
    const float* W_e2 = (const float*)d_in[18];
    // b_e2 cancels under BN
    const float* g_e2 = (const float*)d_in[20];
    const float* be_e2= (const float*)d_in[21];
    const float* W_o1 = (const float*)d_in[22];
    const float* b_o1 = (const float*)d_in[23];   // pre-leaky: must apply
    const float* g_o  = (const float*)d_in[24];
    const float* be_o = (const float*)d_in[25];
    const float* W_o2 = (const float*)d_in[26];
    const float* b_o2 = (const float*)d_in[27];

    // ---- workspace layout ----
    char* w = (char*)d_ws;
    bf16_t* aggbD = (bf16_t*)w;  w += (size_t)BB * 1024 * 2;
    bf16_t* aggbP = (bf16_t*)w;  w += (size_t)BB * KP_P * 2;
    bf16_t* featb = (bf16_t*)w;  w += (size_t)BB * LDF * 2;
    bf16_t* Wt_dg = (bf16_t*)w;  w += (size_t)1024 * 1024 * 2;
    bf16_t* Wt_pg = (bf16_t*)w;  w += (size_t)1024 * KP_P * 2;
    bf16_t* Wt_e1 = (bf16_t*)w;  w += (size_t)2048 * KF_P * 2;
    bf16_t* Wt_e2 = (bf16_t*)w;  w += (size_t)1024 * 2048 * 2;
    bf16_t* Wt_o1 = (bf16_t*)w;  w += (size_t)256 * 1024 * 2;
    float*  deg   = (float*)w;   w += (size_t)(ND + NP) * 4;   // degD | degP
    float*  dis   = (float*)w;   w += (size_t)(ND + NP) * 4;   // disD | disP
    int*    map   = (int*)w;     w += (size_t)(ND + NP) * 4;   // mapD | mapP
    int*    cnt   = (int*)w;     w += (size_t)2 * BB * 4;      // cntD | cntP
    int*    start = (int*)w;     w += (size_t)2 * (BB + 8) * 4;
    int*    cur   = (int*)w;     w += (size_t)2 * BB * 4;
    int*    esrc  = (int*)w;     w += (size_t)(ED + EP + 2 * BB) * 4;
    float*  enorm = (float*)w;   w += (size_t)(ED + EP + 2 * BB) * 4;
    float*  Z1    = (float*)w;   w += (size_t)BB * 2048 * 4;
    bf16_t* Z1b   = (bf16_t*)w;  w += (size_t)BB * 2048 * 2;
    float*  Z2    = (float*)w;   w += (size_t)BB * 1024 * 4;
    bf16_t* feat2b= (bf16_t*)w;  w += (size_t)BB * 1024 * 2;
    float*  Z3    = (float*)w;   w += (size_t)BB * 256 * 4;
    float*  stats = (float*)w;   w += 8192 * 4;                // statsE1|statsE2|statsO

    float* degD = deg,      * degP = deg + ND;
    float* disD = dis,      * disP = dis + ND;
    int*   mapD = map,      * mapP = map + ND;
    int*   cntD = cnt,      * cntP = cnt + BB;
    int*   curD = cur,      * curP = cur + BB;
    int*   startD = start,  * startP = start + (BB + 8);
    int*   esrcD = esrc,    * esrcP = esrc + (ED + BB);
    float* enormD = enorm,  * enormP = enorm + (ED + BB);
    float* statsE1 = stats, * statsE2 = stats + 4096, * statsO = stats + 6144;

    float* y     = (float*)d_out;
    float* feat2 = (float*)d_out + BB;

    dim3 blk256(256);

    // ---- zero/poison working state (4 memsets) ----
    hipMemsetAsync(deg, 0, (size_t)(ND + NP) * 4, stream);
    hipMemsetAsync(map, 0xFF, (size_t)(ND + NP) * 4, stream);
    hipMemsetAsync(cnt, 0, (size_t)2 * BB * 4, stream);
    hipMemsetAsync(stats, 0, (size_t)8192 * 4, stream);

    // ---- weights (one launch) ----
    transpose_all<<<dim3(12928), blk256, 0, stream>>>(W_dg, Wt_dg, W_pg, Wt_pg,
                                                      W_e1, Wt_e1, W_e2, Wt_e2, W_o1, Wt_o1);

    // ---- GCN preprocessing, both branches fused ----
    {
        int t1 = ED + EP + 2 * BB;                       // prep1 / prep3
        int t2 = ND + NP + ED + EP + 2 * BB;             // prep2
        prep1<<<dim3((t1 + 255) / 256), blk256, 0, stream>>>(
            d_eidx + ED, d_ew, p_eidx + EP, p_ew, d_index, p_index, degD, degP, mapD, mapP);
        prep2<<<dim3((t2 + 255) / 256), blk256, 0, stream>>>(
            degD, degP, disD, disP, d_eidx + ED, p_eidx + EP, mapD, mapP,
            d_index, p_index, cntD, cntP);
        scan2<<<dim3(2), dim3(1024), 0, stream>>>(cnt, start, cur);
        prep3<<<dim3((t1 + 255) / 256), blk256, 0, stream>>>(
            d_eidx, d_eidx + ED, d_ew, p_eidx, p_eidx + EP, p_ew,
            disD, disP, mapD, mapP, d_index, p_index, curD, curP,
            esrcD, enormD, esrcP, enormP);
        gather2<<<dim3(BB, 15), blk256, 0, stream>>>(
            startD, esrcD, enormD, d_ecfps, startP, esrcP, enormP, p_gos, aggbD, aggbP);
    }

    // ---- branch GEMMs grouped (512 blocks -> 2/CU overlap) ----
    {
        GemmP pd = { aggbD, Wt_dg, nullptr, 0, featb + 1324, LDF, b_dg, 1024, 1 };
        GemmP pp = { aggbP, Wt_pg, nullptr, 0, featb + 2348, LDF, b_pg, KP_P, 1 };
        gemm_two<<<dim3(1024 / 128, BB / 128, 2), blk256, 0, stream>>>(pd, pp);
    }
    fix_dups2<<<dim3(BB, 2), blk256, 0, stream>>>(d_index, mapD, p_index, mapP, featb);

    // ---- dense concat ----
    {
        size_t tot = (size_t)BB * 300 + (size_t)BB * 1024;
        copy_cols2<<<dim3((tot + 255) / 256), blk256, 0, stream>>>(d_vecs, p_emb, featb);
    }

    // ---- e1: Z1 = featb @ W_e1 (+stats); BN+leaky -> Z1b ----
    {
        GemmP pe = { featb, Wt_e1, Z1, 2048, nullptr, 0, nullptr, KF_P, 0 };
        gemm_one<<<dim3(2048 / 128, BB / 128), blk256, 0, stream>>>(pe, statsE1, 2048);
    }
    bn_apply<<<dim3(((size_t)BB * 2048 + 255) / 256), blk256, 0, stream>>>(
        Z1, statsE1, g_e1, be_e1, nullptr, Z1b, 2048, 1, (size_t)BB * 2048);

    // ---- e2: Z2 = Z1b @ W_e2 (+stats); BN+leaky -> feat2 (f32 out) + feat2b ----
    {
        GemmP pe = { Z1b, Wt_e2, Z2, 1024, nullptr, 0, nullptr, 2048, 0 };
        gemm_one<<<dim3(1024 / 128, BB / 128), blk256, 0, stream>>>(pe, statsE2, 1024);
    }
    bn_apply<<<dim3(((size_t)BB * 1024 + 255) / 256), blk256, 0, stream>>>(
        Z2, statsE2, g_e2, be_e2, feat2, feat2b, 1024, 1, (size_t)BB * 1024);

    // ---- o1: Z3 = leaky(feat2b @ W_o1 + b_o1) (+stats); fused BN + dot -> y ----
    {
        GemmP po = { feat2b, Wt_o1, Z3, 256, nullptr, 0, b_o1, 1024, 1 };
        gemm_one<<<dim3(256 / 128, BB / 128), blk256, 0, stream>>>(po, statsO, 256);
    }
    rowdot_bn<<<dim3(BB / 4), blk256, 0, stream>>>(Z3, statsO, g_o, be_o, W_o2, b_o2, y);
}